// Round 9
// baseline (316.343 us; speedup 1.0000x reference)
//
#include <hip/hip_runtime.h>

#define DEVI __device__ __forceinline__

typedef unsigned short u16;
typedef unsigned int   u32;
typedef __attribute__((ext_vector_type(4))) float f32x4;
typedef __attribute__((ext_vector_type(8))) short short8;
typedef __attribute__((ext_vector_type(8))) __bf16 bf16x8;

#define B_   2
#define S_   2048
#define H_   2048
#define NH_  16
#define HD_  128
#define BH_  (B_*NH_)
// 1/sqrt(128) * log2(e)  -> scores land in log2 domain, softmax uses exp2
#define QSCALE 0.12751743f

DEVI u16 f2b(float f){                       // f32 -> bf16 bits, RNE
  u32 u = __builtin_bit_cast(u32, f);
  u32 r = (u + 0x7fffu + ((u >> 16) & 1u)) >> 16;
  return (u16)r;
}
DEVI float b2f(u16 h){
  u32 u = ((u32)h) << 16;
  return __builtin_bit_cast(float, u);
}
DEVI u32 cvt_pk_bf16(float lo, float hi){    // word = {lo: bf16(lo), hi: bf16(hi)}
  u32 r; asm("v_cvt_pk_bf16_f32 %0, %1, %2" : "=v"(r) : "v"(lo), "v"(hi)); return r;
}
DEVI f32x4 mfma_bf16(short8 a, short8 b, f32x4 c){
  return __builtin_amdgcn_mfma_f32_16x16x32_bf16(
      __builtin_bit_cast(bf16x8, a), __builtin_bit_cast(bf16x8, b), c, 0, 0, 0);
}
DEVI void gl_lds16(const void* g, void* l){
  __builtin_amdgcn_global_load_lds((const __attribute__((address_space(1))) void*)g,
                                   (__attribute__((address_space(3))) void*)l, 16, 0, 0);
}

// Stage a 16KB tile (1024 x 16B chunks) into LDS with XOR swizzle applied on the
// GLOBAL source column (LDS dest stays linear; read side applies the same XOR).
template<int LOG2CPR>
DEVI void stage_swz(const u16* __restrict__ src, int srcStride /*elems*/, u16* lds, int tid){
  const int wid = tid >> 6, lane = tid & 63;
#pragma unroll
  for (int i = 0; i < 4; ++i){
    int lin = i*256 + wid*64 + lane;                       // 16B chunk index
    int row = lin >> LOG2CPR;
    int cb  = ((lin & ((1 << LOG2CPR) - 1)) * 16) ^ ((row & 7) << 4);
    gl_lds16(src + (size_t)row * srcStride + (cb >> 1),
             lds + (size_t)(i*256 + wid*64) * 8);          // wave-uniform LDS base
  }
}

// ---------------- fused f32 -> bf16 convert (x, wq, wk, wv, wo) ----------------
__global__ __launch_bounds__(256) void cvt5_kernel(
    const float* __restrict__ x,  const float* __restrict__ wq,
    const float* __restrict__ wk, const float* __restrict__ wv,
    const float* __restrict__ wo, u16* __restrict__ xb,
    u16* __restrict__ wqkv, u16* __restrict__ wob){
  int i = blockIdx.x * 256 + threadIdx.x;          // [0, 6291456)
  const float* src; u16* dst; int off;
  if      (i < 2097152){ src = x;  dst = xb;             off = i;           }
  else if (i < 3145728){ src = wq; dst = wqkv;           off = i - 2097152; }
  else if (i < 4194304){ src = wk; dst = wqkv + 4194304; off = i - 3145728; }
  else if (i < 5242880){ src = wv; dst = wqkv + 8388608; off = i - 4194304; }
  else                 { src = wo; dst = wob;            off = i - 5242880; }
  float4 v = ((const float4*)src)[off];
  uint2 o;
  o.x = (u32)f2b(v.x) | ((u32)f2b(v.y) << 16);
  o.y = (u32)f2b(v.z) | ((u32)f2b(v.w) << 16);
  ((uint2*)dst)[off] = o;
}

// ---------------- GEMM C = A * B^T  (A [M][K] bf16 rm, Bw [N][K] bf16 rm) ----------------
// 128x128 tile, BK=64, 4 waves (2x2, each 64x64), mfma 16x16x32 bf16.
// EPI 0: write f32 to C [M][N].  EPI 1: scatter bf16 into Q/K/V [B,NH,S,HD].
template<int EPI>
__global__ __launch_bounds__(256) void gemm_bt(
    const u16* __restrict__ A, const u16* __restrict__ Bw,
    float* __restrict__ C, u16* __restrict__ Qd, u16* __restrict__ Kd, u16* __restrict__ Vd,
    int M, int N, int K)
{
  __shared__ __align__(16) u16 As[128*64];
  __shared__ __align__(16) u16 Bs[128*64];
  const int tid  = threadIdx.x, lane = tid & 63, wid = tid >> 6;
  const int wr   = wid >> 1, wc = wid & 1;
  const int lrow = lane & 15, lk = lane >> 4;
  const int RB = blockIdx.y * 128, CB = blockIdx.x * 128;
  f32x4 acc[4][4] = {};

  for (int k0 = 0; k0 < K; k0 += 64){
    __syncthreads();
    stage_swz<3>(A  + (size_t)RB * K + k0, K, As, tid);
    stage_swz<3>(Bw + (size_t)CB * K + k0, K, Bs, tid);
    __syncthreads();
#pragma unroll
    for (int kk = 0; kk < 2; ++kk){
      short8 af[4], bf[4];
#pragma unroll
      for (int m = 0; m < 4; ++m){
        int row = wr*64 + m*16 + lrow;
        int cb  = (kk*64 + lk*16) ^ ((row & 7) << 4);
        af[m] = *(const short8*)&As[row*64 + (cb >> 1)];
      }
#pragma unroll
      for (int n = 0; n < 4; ++n){
        int row = wc*64 + n*16 + lrow;
        int cb  = (kk*64 + lk*16) ^ ((row & 7) << 4);
        bf[n] = *(const short8*)&Bs[row*64 + (cb >> 1)];
      }
#pragma unroll
      for (int m = 0; m < 4; ++m)
#pragma unroll
        for (int n = 0; n < 4; ++n)
          acc[m][n] = mfma_bf16(af[m], bf[n], acc[m][n]);
    }
  }

#pragma unroll
  for (int m = 0; m < 4; ++m){
#pragma unroll
    for (int n = 0; n < 4; ++n){
#pragma unroll
      for (int r = 0; r < 4; ++r){
        int row = RB + wr*64 + m*16 + lk*4 + r;
        int col = CB + wc*64 + n*16 + lrow;
        float v = acc[m][n][r];
        if constexpr (EPI == 0){
          C[(size_t)row * N + col] = v;
        } else {
          int which = col >> 11;
          int hd = col & 2047;
          int h = hd >> 7, d = hd & 127;
          int b = row >> 11, s = row & 2047;
          u16* dst = (which == 0) ? Qd : (which == 1) ? Kd : Vd;
          dst[(((size_t)(b*NH_ + h)) * S_ + s) * HD_ + d] = f2b(v);
        }
      }
    }
  }
}

// ---------------- RoPE (in place on Q,K; Q also scaled by QSCALE) ----------------
__global__ __launch_bounds__(256) void rope_kernel(u16* __restrict__ Q, u16* __restrict__ K,
                                                   const float* __restrict__ F){
  int idx = blockIdx.x * 256 + threadIdx.x;   // BH*S*64
  int d2 = idx & 63;
  int s  = (idx >> 6) & (S_ - 1);
  int bh = idx >> 17;
  size_t off = ((size_t)bh * S_ + s) * HD_ + d2*2;
  float c = F[s*128 + d2*2], sn = F[s*128 + d2*2 + 1];
  u32 qp = *(const u32*)(Q + off);
  float tr = b2f((u16)qp), ti = b2f((u16)(qp >> 16));
  float q0 = (tr*c - ti*sn) * QSCALE, q1 = (tr*sn + ti*c) * QSCALE;
  *(u32*)(Q + off) = (u32)f2b(q0) | ((u32)f2b(q1) << 16);
  u32 kp = *(const u32*)(K + off);
  tr = b2f((u16)kp); ti = b2f((u16)(kp >> 16));
  float k0 = tr*c - ti*sn, k1 = tr*sn + ti*c;
  *(u32*)(K + off) = (u32)f2b(k0) | ((u32)f2b(k1) << 16);
}

// ---------------- V transpose: [BH,S,HD] -> [BH,HD,S] ----------------
__global__ void transpose_v(const u16* __restrict__ V, u16* __restrict__ Vt){
  __shared__ u16 t[32][33];
  int s0 = blockIdx.x * 32, d0 = blockIdx.y * 32, bh = blockIdx.z;
  const u16* vb = V  + (size_t)bh * S_ * HD_;
  u16*       tb = Vt + (size_t)bh * HD_ * S_;
  int tx = threadIdx.x, ty = threadIdx.y;
#pragma unroll
  for (int i = 0; i < 4; ++i)
    t[ty + i*8][tx] = vb[(size_t)(s0 + ty + i*8) * HD_ + d0 + tx];
  __syncthreads();
#pragma unroll
  for (int i = 0; i < 4; ++i)
    tb[(size_t)(d0 + ty + i*8) * S_ + s0 + tx] = t[tx][ty + i*8];
}

// raw barriers with counted waits (NOT __syncthreads: no full vmcnt drain)
#define BAR_MID() do{ asm volatile("s_waitcnt lgkmcnt(0)" ::: "memory"); \
                      __builtin_amdgcn_s_barrier(); } while(0)
#define BAR_END() do{ asm volatile("s_waitcnt vmcnt(8) lgkmcnt(0)" ::: "memory"); \
                      __builtin_amdgcn_s_barrier(); } while(0)

// ---------------- Flash attention (causal), pair-balanced, pipelined ----------------
// 512 blocks (2/CU). Each block: complementary q-stripes 31-x then x (33 tiles, uniform).
// 4 waves x 16 q rows (QBLK=64), KVBLK=64.
// PIPELINE (1-tile lag): iter t issues QK(t) MFMA, then does softmax+PV on tile t-1 --
// QK latency hides under softmax VALU. Counted vmcnt: end-barrier waits vmcnt(8)
// = {V(t), K(t+1)} leaving V(t+1) in flight; V(t+1) staged after mid-barrier
// (write-after-read safety on the Vs slot). No vmcnt(0) drain in the loop.
// Swapped QK^T: S^T[kv][q] = mfma(A=K, B=Q)  -> per-lane softmax (q = lane&15).
// Flipped PV:   O^T[d][q]  = mfma(A=V^T, B=P) -> no cross-lane rescale/normalize.
// Scores in log2 domain (log2e folded into rope Q scale); softmax = exp2.
__global__ __launch_bounds__(256) void attn_kernel(
    const u16* __restrict__ Q, const u16* __restrict__ K, const u16* __restrict__ Vt,
    u16* __restrict__ O)
{
  __shared__ __align__(16) u16 Ks[2][64*128];  // [kv][d], swizzled    32 KB
  __shared__ __align__(16) u16 Vs[2][128*64];  // [d][kv], swizzled    32 KB
  __shared__ __align__(16) u16 Ps[4][16*64];   // per-wave P [16q][64kv], XOR-swz  8 KB
  const int tid  = threadIdx.x, lane = tid & 63, wid = tid >> 6;
  const int lrow = lane & 15, lk = lane >> 4;

  const int lin = blockIdx.x;
  const int bh  = (lin & 7) | ((lin >> 7) << 3);   // bh ≡ XCD (mod 8) -> L2 locality
  const int x   = (lin >> 3) & 15;

  const u16* Kb  = K  + (size_t)bh * S_ * HD_;
  const u16* Vtb = Vt + (size_t)bh * HD_ * S_;
  const int b = bh >> 4, h = bh & 15;
  u16* const pw = &Ps[wid][0];

  for (int pass = 0; pass < 2; ++pass){
    const int qb = pass ? x : (31 - x);
    const int q0 = qb * 64;
    const int ntile = qb + 1;
    const int qg = q0 + wid*16 + lrow;        // this lane's q row (B-frag col)

    // Q fragments (B-operand): col q = qg, k = kc*32 + lk*8 + j
    short8 qf[4];
    {
      const u16* qp_ = Q + ((size_t)bh * S_ + qg) * HD_;
#pragma unroll
      for (int kc = 0; kc < 4; ++kc) qf[kc] = *(const short8*)&qp_[kc*32 + lk*8];
    }

    f32x4 acco[8] = {};
    f32x4 scp[4];                             // previous tile's scores (pipeline reg)
    float m_ = -3.0e38f, l_ = 0.0f;

    // prologue: stage tile 0, full drain
    stage_swz<4>(Kb,  HD_, &Ks[0][0], tid);
    stage_swz<3>(Vtb, S_,  &Vs[0][0], tid);
    __syncthreads();

    // ---- peeled iter 0: QK(0) only (no previous tile) ----
    {
      if (1 < ntile) stage_swz<4>(Kb + (size_t)64*HD_, HD_, &Ks[1][0], tid);
      const u16* ks = &Ks[0][0];
#pragma unroll
      for (int nt = 0; nt < 4; ++nt){
        f32x4 a = {0.f,0.f,0.f,0.f};
        int row = nt*16 + lrow;
#pragma unroll
        for (int kc = 0; kc < 4; ++kc){
          int cb = (kc*64 + lk*16) ^ ((row & 7) << 4);
          short8 kf = *(const short8*)&ks[row*128 + (cb >> 1)];
          a = mfma_bf16(kf, qf[kc], a);
        }
        scp[nt] = a;
      }
      if (ntile == 1){  // tile 0 is diagonal
#pragma unroll
        for (int nt = 0; nt < 4; ++nt)
#pragma unroll
          for (int r = 0; r < 4; ++r)
            if (nt*16 + lk*4 + r > qg) scp[nt][r] = -1.0e30f;
      }
      BAR_MID();
      if (1 < ntile) stage_swz<3>(Vtb + 64, S_, &Vs[1][0], tid);
      BAR_END();
    }

    // ---- main loop: iter t does QK(t) then softmax+PV(t-1); t==ntile is tail ----
    for (int t = 1; t <= ntile; ++t){
      const int cur = t & 1;
      f32x4 scn[4];
      if (t < ntile){
        if (t + 1 < ntile) stage_swz<4>(Kb + (size_t)(t+1)*64*HD_, HD_, &Ks[cur^1][0], tid);
        const u16* ks = &Ks[cur][0];
        __builtin_amdgcn_s_setprio(1);
#pragma unroll
        for (int nt = 0; nt < 4; ++nt){
          f32x4 a = {0.f,0.f,0.f,0.f};
          int row = nt*16 + lrow;
#pragma unroll
          for (int kc = 0; kc < 4; ++kc){
            int cb = (kc*64 + lk*16) ^ ((row & 7) << 4);
            short8 kf = *(const short8*)&ks[row*128 + (cb >> 1)];
            a = mfma_bf16(kf, qf[kc], a);
          }
          scn[nt] = a;
        }
        __builtin_amdgcn_s_setprio(0);
        if (t == ntile - 1){  // diagonal tile: causal mask at production
          const int kv0 = t*64;
#pragma unroll
          for (int nt = 0; nt < 4; ++nt)
#pragma unroll
            for (int r = 0; r < 4; ++r)
              if (kv0 + nt*16 + lk*4 + r > qg) scn[nt][r] = -1.0e30f;
        }
      } else {
        asm volatile("s_waitcnt vmcnt(0)" ::: "memory");   // V(ntile-1) landed
      }

      // ---- softmax on tile t-1 (per-lane, exp2 domain) + P pack/store ----
      {
        float pmax = scp[0][0];
#pragma unroll
        for (int nt = 0; nt < 4; ++nt)
#pragma unroll
          for (int r = 0; r < 4; ++r) pmax = fmaxf(pmax, scp[nt][r]);
        pmax = fmaxf(pmax, __shfl_xor(pmax, 16));
        pmax = fmaxf(pmax, __shfl_xor(pmax, 32));
        if (!__all(pmax - m_ <= 11.0f)){        // defer-max (log2-domain THR)
          float mn = fmaxf(m_, pmax);
          float c = exp2f(m_ - mn);
          l_ *= c;
#pragma unroll
          for (int dt = 0; dt < 8; ++dt)
#pragma unroll
            for (int r = 0; r < 4; ++r) acco[dt][r] *= c;
          m_ = mn;
        }
        float rs = 0.0f;
#pragma unroll
        for (int nt = 0; nt < 4; ++nt)
#pragma unroll
          for (int r = 0; r < 4; ++r){
            float p = exp2f(scp[nt][r] - m_);
            scp[nt][r] = p;
            rs += p;
          }
        rs += __shfl_xor(rs, 16);
        rs += __shfl_xor(rs, 32);
        l_ += rs;
#pragma unroll
        for (int nt = 0; nt < 4; ++nt){
          uint2 wv;
          wv.x = cvt_pk_bf16(scp[nt][0], scp[nt][1]);
          wv.y = cvt_pk_bf16(scp[nt][2], scp[nt][3]);
          int boff = (nt*32 + lk*8) ^ ((lrow & 7) << 4);
          *(uint2*)((char*)&pw[lrow*64] + boff) = wv;
        }
      }

      // ---- PV on tile t-1: acco += V(t-1)^T x P,  V(t-1) in Vs[(t-1)&1] ----
      {
        const u16* vs = &Vs[cur^1][0];
#pragma unroll
        for (int kc2 = 0; kc2 < 2; ++kc2){
          int pboff = (kc2*64 + lk*16) ^ ((lrow & 7) << 4);
          short8 pf = *(const short8*)((const char*)&pw[lrow*64] + pboff);
          __builtin_amdgcn_s_setprio(1);
#pragma unroll
          for (int dt = 0; dt < 8; ++dt){
            int row = dt*16 + lrow;
            int cb = (kc2*64 + lk*16) ^ ((row & 7) << 4);
            short8 vf = *(const short8*)&vs[row*64 + (cb >> 1)];
            acco[dt] = mfma_bf16(vf, pf, acco[dt]);
          }
          __builtin_amdgcn_s_setprio(0);
        }
      }

      if (t < ntile){
        BAR_MID();            // all waves done reading Vs[cur^1] (V(t-1))
        if (t + 1 < ntile) stage_swz<3>(Vtb + (t+1)*64, S_, &Vs[cur^1][0], tid);
#pragma unroll
        for (int nt = 0; nt < 4; ++nt) scp[nt] = scn[nt];
        BAR_END();            // vmcnt(8): waits {V(t), K(t+1)}, leaves V(t+1) flying
      }
    }

    // ---- epilogue: normalize + packed store ----
    {
      float inv = 1.0f / l_;
      u16* ob = O + ((size_t)(b*S_ + qg)) * H_ + h*128;
#pragma unroll
      for (int dt = 0; dt < 8; ++dt){
        uint2 wv;
        wv.x = cvt_pk_bf16(acco[dt][0]*inv, acco[dt][1]*inv);
        wv.y = cvt_pk_bf16(acco[dt][2]*inv, acco[dt][3]*inv);
        *(uint2*)&ob[dt*16 + lk*4] = wv;
      }
    }
    __syncthreads();       // pass boundary: full drain, LDS reuse safe
  }
}

// ---------------- launch ----------------
extern "C" void kernel_launch(void* const* d_in, const int* in_sizes, int n_in,
                              void* d_out, int out_size, void* d_ws, size_t ws_size,
                              hipStream_t stream)
{
  (void)in_sizes; (void)n_in; (void)out_size; (void)ws_size;
  const float* x  = (const float*)d_in[0];
  const float* fc = (const float*)d_in[1];   // freqs_cis [S,64,2]
  const float* wq = (const float*)d_in[3];
  const float* wk = (const float*)d_in[4];
  const float* wv = (const float*)d_in[5];
  const float* wo = (const float*)d_in[6];

  char* w = (char*)d_ws;
  u16* xb   = (u16*)(w);                 // [4096,2048] bf16
  u16* wqkv = (u16*)(w + 16777216);      // [6144,2048] bf16
  u16* wob  = (u16*)(w + 41943040);      // [2048,2048] bf16
  u16* Qr   = (u16*)(w + 50331648);      // [BH,S,HD]   bf16
  u16* Kr   = (u16*)(w + 67108864);      // [BH,S,HD]   bf16
  u16* Vr   = (u16*)(w + 83886080);      // [BH,S,HD]   bf16
  u16* Vt   = (u16*)(w + 100663296);     // [BH,HD,S]   bf16
  u16* aO   = (u16*)(w + 117440512);     // [B,S,H]     bf16 (attn out)
  float* out = (float*)d_out;

  cvt5_kernel<<<24576, 256, 0, stream>>>(x, wq, wk, wv, wo, xb, wqkv, wob);

  gemm_bt<1><<<dim3(48, 32), 256, 0, stream>>>(xb, wqkv, nullptr, Qr, Kr, Vr, 4096, 6144, 2048);
  rope_kernel<<<16384, 256, 0, stream>>>(Qr, Kr, fc);
  transpose_v<<<dim3(64, 4, 32), dim3(32, 8), 0, stream>>>(Vr, Vt);
  attn_kernel<<<512, 256, 0, stream>>>(Qr, Kr, Vt, aO);
  gemm_bt<0><<<dim3(16, 32), 256, 0, stream>>>(aO, wob, out, nullptr, nullptr, nullptr, 4096, 2048, 2048);
}

// Round 10
// 291.215 us; speedup vs baseline: 1.0863x; 1.0863x over previous
//
#include <hip/hip_runtime.h>

#define DEVI __device__ __forceinline__

typedef unsigned short u16;
typedef unsigned int   u32;
typedef __attribute__((ext_vector_type(4))) float f32x4;
typedef __attribute__((ext_vector_type(8))) short short8;
typedef __attribute__((ext_vector_type(8))) __bf16 bf16x8;

#define B_   2
#define S_   2048
#define H_   2048
#define NH_  16
#define HD_  128
#define BH_  (B_*NH_)
// 1/sqrt(128) * log2(e)  -> scores land in log2 domain, softmax uses exp2
#define QSCALE 0.12751743f

DEVI u16 f2b(float f){                       // f32 -> bf16 bits, RNE
  u32 u = __builtin_bit_cast(u32, f);
  u32 r = (u + 0x7fffu + ((u >> 16) & 1u)) >> 16;
  return (u16)r;
}
DEVI float b2f(u16 h){
  u32 u = ((u32)h) << 16;
  return __builtin_bit_cast(float, u);
}
DEVI u32 cvt_pk_bf16(float lo, float hi){    // word = {lo: bf16(lo), hi: bf16(hi)}
  u32 r; asm("v_cvt_pk_bf16_f32 %0, %1, %2" : "=v"(r) : "v"(lo), "v"(hi)); return r;
}
DEVI f32x4 mfma_bf16(short8 a, short8 b, f32x4 c){
  return __builtin_amdgcn_mfma_f32_16x16x32_bf16(
      __builtin_bit_cast(bf16x8, a), __builtin_bit_cast(bf16x8, b), c, 0, 0, 0);
}
DEVI void gl_lds16(const void* g, void* l){
  __builtin_amdgcn_global_load_lds((const __attribute__((address_space(1))) void*)g,
                                   (__attribute__((address_space(3))) void*)l, 16, 0, 0);
}

// Stage a 16KB tile (1024 x 16B chunks) into LDS with XOR swizzle applied on the
// GLOBAL source column (LDS dest stays linear; read side applies the same XOR).
template<int LOG2CPR>
DEVI void stage_swz(const u16* __restrict__ src, int srcStride /*elems*/, u16* lds, int tid){
  const int wid = tid >> 6, lane = tid & 63;
#pragma unroll
  for (int i = 0; i < 4; ++i){
    int lin = i*256 + wid*64 + lane;                       // 16B chunk index
    int row = lin >> LOG2CPR;
    int cb  = ((lin & ((1 << LOG2CPR) - 1)) * 16) ^ ((row & 7) << 4);
    gl_lds16(src + (size_t)row * srcStride + (cb >> 1),
             lds + (size_t)(i*256 + wid*64) * 8);          // wave-uniform LDS base
  }
}

// ---------------- fused f32 -> bf16 convert (x, wq, wk, wv, wo) ----------------
__global__ __launch_bounds__(256) void cvt5_kernel(
    const float* __restrict__ x,  const float* __restrict__ wq,
    const float* __restrict__ wk, const float* __restrict__ wv,
    const float* __restrict__ wo, u16* __restrict__ xb,
    u16* __restrict__ wqkv, u16* __restrict__ wob){
  int i = blockIdx.x * 256 + threadIdx.x;          // [0, 6291456)
  const float* src; u16* dst; int off;
  if      (i < 2097152){ src = x;  dst = xb;             off = i;           }
  else if (i < 3145728){ src = wq; dst = wqkv;           off = i - 2097152; }
  else if (i < 4194304){ src = wk; dst = wqkv + 4194304; off = i - 3145728; }
  else if (i < 5242880){ src = wv; dst = wqkv + 8388608; off = i - 4194304; }
  else                 { src = wo; dst = wob;            off = i - 5242880; }
  float4 v = ((const float4*)src)[off];
  uint2 o;
  o.x = (u32)f2b(v.x) | ((u32)f2b(v.y) << 16);
  o.y = (u32)f2b(v.z) | ((u32)f2b(v.w) << 16);
  ((uint2*)dst)[off] = o;
}

// ---------------- GEMM C = A * B^T  (A [M][K] bf16 rm, Bw [N][K] bf16 rm) ----------------
// 128x128 tile, BK=64, 4 waves (2x2, each 64x64), mfma 16x16x32 bf16.
// EPI 0: write f32 to C [M][N].  EPI 1: scatter bf16 into Q/K/V [B,NH,S,HD].
template<int EPI>
__global__ __launch_bounds__(256) void gemm_bt(
    const u16* __restrict__ A, const u16* __restrict__ Bw,
    float* __restrict__ C, u16* __restrict__ Qd, u16* __restrict__ Kd, u16* __restrict__ Vd,
    int M, int N, int K)
{
  __shared__ __align__(16) u16 As[128*64];
  __shared__ __align__(16) u16 Bs[128*64];
  const int tid  = threadIdx.x, lane = tid & 63, wid = tid >> 6;
  const int wr   = wid >> 1, wc = wid & 1;
  const int lrow = lane & 15, lk = lane >> 4;
  const int RB = blockIdx.y * 128, CB = blockIdx.x * 128;
  f32x4 acc[4][4] = {};

  for (int k0 = 0; k0 < K; k0 += 64){
    __syncthreads();
    stage_swz<3>(A  + (size_t)RB * K + k0, K, As, tid);
    stage_swz<3>(Bw + (size_t)CB * K + k0, K, Bs, tid);
    __syncthreads();
#pragma unroll
    for (int kk = 0; kk < 2; ++kk){
      short8 af[4], bf[4];
#pragma unroll
      for (int m = 0; m < 4; ++m){
        int row = wr*64 + m*16 + lrow;
        int cb  = (kk*64 + lk*16) ^ ((row & 7) << 4);
        af[m] = *(const short8*)&As[row*64 + (cb >> 1)];
      }
#pragma unroll
      for (int n = 0; n < 4; ++n){
        int row = wc*64 + n*16 + lrow;
        int cb  = (kk*64 + lk*16) ^ ((row & 7) << 4);
        bf[n] = *(const short8*)&Bs[row*64 + (cb >> 1)];
      }
#pragma unroll
      for (int m = 0; m < 4; ++m)
#pragma unroll
        for (int n = 0; n < 4; ++n)
          acc[m][n] = mfma_bf16(af[m], bf[n], acc[m][n]);
    }
  }

#pragma unroll
  for (int m = 0; m < 4; ++m){
#pragma unroll
    for (int n = 0; n < 4; ++n){
#pragma unroll
      for (int r = 0; r < 4; ++r){
        int row = RB + wr*64 + m*16 + lk*4 + r;
        int col = CB + wc*64 + n*16 + lrow;
        float v = acc[m][n][r];
        if constexpr (EPI == 0){
          C[(size_t)row * N + col] = v;
        } else {
          int which = col >> 11;
          int hd = col & 2047;
          int h = hd >> 7, d = hd & 127;
          int b = row >> 11, s = row & 2047;
          u16* dst = (which == 0) ? Qd : (which == 1) ? Kd : Vd;
          dst[(((size_t)(b*NH_ + h)) * S_ + s) * HD_ + d] = f2b(v);
        }
      }
    }
  }
}

// ---------------- RoPE (in place on Q,K; Q also scaled by QSCALE) ----------------
__global__ __launch_bounds__(256) void rope_kernel(u16* __restrict__ Q, u16* __restrict__ K,
                                                   const float* __restrict__ F){
  int idx = blockIdx.x * 256 + threadIdx.x;   // BH*S*64
  int d2 = idx & 63;
  int s  = (idx >> 6) & (S_ - 1);
  int bh = idx >> 17;
  size_t off = ((size_t)bh * S_ + s) * HD_ + d2*2;
  float c = F[s*128 + d2*2], sn = F[s*128 + d2*2 + 1];
  u32 qp = *(const u32*)(Q + off);
  float tr = b2f((u16)qp), ti = b2f((u16)(qp >> 16));
  float q0 = (tr*c - ti*sn) * QSCALE, q1 = (tr*sn + ti*c) * QSCALE;
  *(u32*)(Q + off) = (u32)f2b(q0) | ((u32)f2b(q1) << 16);
  u32 kp = *(const u32*)(K + off);
  tr = b2f((u16)kp); ti = b2f((u16)(kp >> 16));
  float k0 = tr*c - ti*sn, k1 = tr*sn + ti*c;
  *(u32*)(K + off) = (u32)f2b(k0) | ((u32)f2b(k1) << 16);
}

// ---------------- V transpose: [BH,S,HD] -> [BH,HD,S] ----------------
__global__ void transpose_v(const u16* __restrict__ V, u16* __restrict__ Vt){
  __shared__ u16 t[32][33];
  int s0 = blockIdx.x * 32, d0 = blockIdx.y * 32, bh = blockIdx.z;
  const u16* vb = V  + (size_t)bh * S_ * HD_;
  u16*       tb = Vt + (size_t)bh * HD_ * S_;
  int tx = threadIdx.x, ty = threadIdx.y;
#pragma unroll
  for (int i = 0; i < 4; ++i)
    t[ty + i*8][tx] = vb[(size_t)(s0 + ty + i*8) * HD_ + d0 + tx];
  __syncthreads();
#pragma unroll
  for (int i = 0; i < 4; ++i)
    tb[(size_t)(d0 + ty + i*8) * S_ + s0 + tx] = t[tx][ty + i*8];
}

// ---------------- Flash attention (causal), pair-balanced, QBLK=64, 4 blocks/CU ----
// LDS = 16(K) + 16(V) + 8(P) = 40 KB -> 4 blocks/CU = 4 waves/SIMD. The per-tile
// chain (QK MFMA -> serial softmax -> P LDS -> PV MFMA) is latency-bound; 4
// independent block-chains per SIMD fill the pipes (TLP beats dbuf prefetch here:
// exposed stage latency ~400cyc << chain ~1300cyc is covered by other blocks).
// Single-buffered K/V, 2 barriers/tile (read-fence, data-fence).
// 512 blocks: complementary q-stripes 31-x then x (33 tiles/block, uniform).
// Swapped QK^T: S^T[kv][q] = mfma(A=K, B=Q)  -> per-lane softmax (q = lane&15).
// Flipped PV:   O^T[d][q]  = mfma(A=V^T, B=P) -> no cross-lane rescale/normalize.
// Scores in log2 domain (log2e folded into rope Q scale); softmax = exp2.
__global__ __launch_bounds__(256, 4) void attn_kernel(
    const u16* __restrict__ Q, const u16* __restrict__ K, const u16* __restrict__ Vt,
    u16* __restrict__ O)
{
  __shared__ __align__(16) u16 Ks[64*128];   // [kv][d], swizzled   16 KB
  __shared__ __align__(16) u16 Vs[128*64];   // [d][kv], swizzled   16 KB
  __shared__ __align__(16) u16 Ps[4][16*64]; // per-wave P [16q][64kv], XOR-swz  8 KB
  const int tid  = threadIdx.x, lane = tid & 63, wid = tid >> 6;
  const int lrow = lane & 15, lk = lane >> 4;

  // XCD-locality swizzle: lin%8 = XCD (heuristic); bh ≡ XCD (mod 8) ->
  // 4 distinct bh per XCD -> K/V working set ~4MB = one L2.
  const int lin = blockIdx.x;
  const int bh  = (lin & 7) | ((lin >> 7) << 3);
  const int x   = (lin >> 3) & 15;

  const u16* Kb  = K  + (size_t)bh * S_ * HD_;
  const u16* Vtb = Vt + (size_t)bh * HD_ * S_;
  const int b = bh >> 4, h = bh & 15;
  u16* const pw = &Ps[wid][0];

  for (int pass = 0; pass < 2; ++pass){
    const int qb = pass ? x : (31 - x);
    const int q0 = qb * 64;
    const int ntile = qb + 1;
    const int qg = q0 + wid*16 + lrow;        // this lane's q row (B-frag col)

    // Q fragments (B-operand): col q = qg, k = kc*32 + lk*8 + j
    short8 qf[4];
    {
      const u16* qp_ = Q + ((size_t)bh * S_ + qg) * HD_;
#pragma unroll
      for (int kc = 0; kc < 4; ++kc) qf[kc] = *(const short8*)&qp_[kc*32 + lk*8];
    }

    f32x4 acco[8] = {};
    float m_ = -3.0e38f, l_ = 0.0f;

    for (int t = 0; t < ntile; ++t){
      __syncthreads();                         // all waves done reading previous tile
      stage_swz<4>(Kb  + (size_t)t*64*HD_, HD_, Ks, tid);
      stage_swz<3>(Vtb + t*64,             S_,  Vs, tid);
      __syncthreads();                         // drains vmcnt(0): staged tile visible

      const int kv0 = t*64;

      // ---- QK^T (swapped): sc[nt] = S^T[kv][q] ----
      f32x4 sc[4] = {};
      __builtin_amdgcn_s_setprio(1);
#pragma unroll
      for (int nt = 0; nt < 4; ++nt){
        int row = nt*16 + lrow;
#pragma unroll
        for (int kc = 0; kc < 4; ++kc){
          int cb = (kc*64 + lk*16) ^ ((row & 7) << 4);
          short8 kf = *(const short8*)&Ks[row*128 + (cb >> 1)];
          sc[nt] = mfma_bf16(kf, qf[kc], sc[nt]);
        }
      }
      __builtin_amdgcn_s_setprio(0);

      if (t == ntile - 1){   // diagonal tile: causal mask
#pragma unroll
        for (int nt = 0; nt < 4; ++nt)
#pragma unroll
          for (int r = 0; r < 4; ++r)
            if (kv0 + nt*16 + lk*4 + r > qg) sc[nt][r] = -1.0e30f;
      }

      // ---- per-lane online softmax (exp2 domain) + P pack/store ----
      {
        float pmax = sc[0][0];
#pragma unroll
        for (int nt = 0; nt < 4; ++nt)
#pragma unroll
          for (int r = 0; r < 4; ++r) pmax = fmaxf(pmax, sc[nt][r]);
        pmax = fmaxf(pmax, __shfl_xor(pmax, 16));
        pmax = fmaxf(pmax, __shfl_xor(pmax, 32));
        if (!__all(pmax - m_ <= 11.0f)){        // defer-max (log2-domain THR)
          float mn = fmaxf(m_, pmax);
          float c = exp2f(m_ - mn);
          l_ *= c;
#pragma unroll
          for (int dt = 0; dt < 8; ++dt)
#pragma unroll
            for (int r = 0; r < 4; ++r) acco[dt][r] *= c;
          m_ = mn;
        }
        float rs = 0.0f;
#pragma unroll
        for (int nt = 0; nt < 4; ++nt)
#pragma unroll
          for (int r = 0; r < 4; ++r){
            float p = exp2f(sc[nt][r] - m_);
            sc[nt][r] = p;
            rs += p;
          }
        rs += __shfl_xor(rs, 16);
        rs += __shfl_xor(rs, 32);
        l_ += rs;
#pragma unroll
        for (int nt = 0; nt < 4; ++nt){
          uint2 wv;
          wv.x = cvt_pk_bf16(sc[nt][0], sc[nt][1]);
          wv.y = cvt_pk_bf16(sc[nt][2], sc[nt][3]);
          int boff = (nt*32 + lk*8) ^ ((lrow & 7) << 4);
          *(uint2*)((char*)&pw[lrow*64] + boff) = wv;
        }
      }

      // ---- PV (flipped): acco[dt] += V^T x P ----
#pragma unroll
      for (int kc2 = 0; kc2 < 2; ++kc2){
        int pboff = (kc2*64 + lk*16) ^ ((lrow & 7) << 4);
        short8 pf = *(const short8*)((const char*)&pw[lrow*64] + pboff);
        __builtin_amdgcn_s_setprio(1);
#pragma unroll
        for (int dt = 0; dt < 8; ++dt){
          int row = dt*16 + lrow;
          int cb = (kc2*64 + lk*16) ^ ((row & 7) << 4);
          short8 vf = *(const short8*)&Vs[row*64 + (cb >> 1)];
          acco[dt] = mfma_bf16(vf, pf, acco[dt]);
        }
        __builtin_amdgcn_s_setprio(0);
      }
    }

    // ---- epilogue: normalize + packed store ----
    {
      float inv = 1.0f / l_;
      u16* ob = O + ((size_t)(b*S_ + qg)) * H_ + h*128;
#pragma unroll
      for (int dt = 0; dt < 8; ++dt){
        uint2 wv;
        wv.x = cvt_pk_bf16(acco[dt][0]*inv, acco[dt][1]*inv);
        wv.y = cvt_pk_bf16(acco[dt][2]*inv, acco[dt][3]*inv);
        *(uint2*)&ob[dt*16 + lk*4] = wv;
      }
    }
  }
}

// ---------------- launch ----------------
extern "C" void kernel_launch(void* const* d_in, const int* in_sizes, int n_in,
                              void* d_out, int out_size, void* d_ws, size_t ws_size,
                              hipStream_t stream)
{
  (void)in_sizes; (void)n_in; (void)out_size; (void)ws_size;
  const float* x  = (const float*)d_in[0];
  const float* fc = (const float*)d_in[1];   // freqs_cis [S,64,2]
  const float* wq = (const float*)d_in[3];
  const float* wk = (const float*)d_in[4];
  const float* wv = (const float*)d_in[5];
  const float* wo = (const float*)d_in[6];

  char* w = (char*)d_ws;
  u16* xb   = (u16*)(w);                 // [4096,2048] bf16
  u16* wqkv = (u16*)(w + 16777216);      // [6144,2048] bf16
  u16* wob  = (u16*)(w + 41943040);      // [2048,2048] bf16
  u16* Qr   = (u16*)(w + 50331648);      // [BH,S,HD]   bf16
  u16* Kr   = (u16*)(w + 67108864);      // [BH,S,HD]   bf16
  u16* Vr   = (u16*)(w + 83886080);      // [BH,S,HD]   bf16
  u16* Vt   = (u16*)(w + 100663296);     // [BH,HD,S]   bf16
  u16* aO   = (u16*)(w + 117440512);     // [B,S,H]     bf16 (attn out)
  float* out = (float*)d_out;

  cvt5_kernel<<<24576, 256, 0, stream>>>(x, wq, wk, wv, wo, xb, wqkv, wob);

  gemm_bt<1><<<dim3(48, 32), 256, 0, stream>>>(xb, wqkv, nullptr, Qr, Kr, Vr, 4096, 6144, 2048);
  rope_kernel<<<16384, 256, 0, stream>>>(Qr, Kr, fc);
  transpose_v<<<dim3(64, 4, 32), dim3(32, 8), 0, stream>>>(Vr, Vt);
  attn_kernel<<<512, 256, 0, stream>>>(Qr, Kr, Vt, aO);
  gemm_bt<0><<<dim3(16, 32), 256, 0, stream>>>(aO, wob, out, nullptr, nullptr, nullptr, 4096, 2048, 2048);
}

// Round 11
// 276.193 us; speedup vs baseline: 1.1454x; 1.0544x over previous
//
#include <hip/hip_runtime.h>

#define DEVI __device__ __forceinline__

typedef unsigned short u16;
typedef unsigned int   u32;
typedef __attribute__((ext_vector_type(4))) float f32x4;
typedef __attribute__((ext_vector_type(8))) short short8;
typedef __attribute__((ext_vector_type(8))) __bf16 bf16x8;

#define B_   2
#define S_   2048
#define H_   2048
#define NH_  16
#define HD_  128
#define BH_  (B_*NH_)
// 1/sqrt(128) * log2(e)  -> scores land in log2 domain, softmax uses exp2
#define QSCALE 0.12751743f

DEVI u16 f2b(float f){                       // f32 -> bf16 bits, RNE
  u32 u = __builtin_bit_cast(u32, f);
  u32 r = (u + 0x7fffu + ((u >> 16) & 1u)) >> 16;
  return (u16)r;
}
DEVI float b2f(u16 h){
  u32 u = ((u32)h) << 16;
  return __builtin_bit_cast(float, u);
}
DEVI u32 cvt_pk_bf16(float lo, float hi){    // word = {lo: bf16(lo), hi: bf16(hi)}
  u32 r; asm("v_cvt_pk_bf16_f32 %0, %1, %2" : "=v"(r) : "v"(lo), "v"(hi)); return r;
}
DEVI u32 rot2(u16 lo, u16 hi, float c, float s, float scale){  // RoPE one (even,odd) pair
  float tr = b2f(lo), ti = b2f(hi);
  return cvt_pk_bf16((tr*c - ti*s)*scale, (tr*s + ti*c)*scale);
}
DEVI f32x4 mfma_bf16(short8 a, short8 b, f32x4 c){
  return __builtin_amdgcn_mfma_f32_16x16x32_bf16(
      __builtin_bit_cast(bf16x8, a), __builtin_bit_cast(bf16x8, b), c, 0, 0, 0);
}
DEVI void gl_lds16(const void* g, void* l){
  __builtin_amdgcn_global_load_lds((const __attribute__((address_space(1))) void*)g,
                                   (__attribute__((address_space(3))) void*)l, 16, 0, 0);
}

// Stage a 16KB tile (1024 x 16B chunks) into LDS with XOR swizzle applied on the
// GLOBAL source column (LDS dest stays linear; read side applies the same XOR).
template<int LOG2CPR>
DEVI void stage_swz(const u16* __restrict__ src, int srcStride /*elems*/, u16* lds, int tid){
  const int wid = tid >> 6, lane = tid & 63;
#pragma unroll
  for (int i = 0; i < 4; ++i){
    int lin = i*256 + wid*64 + lane;                       // 16B chunk index
    int row = lin >> LOG2CPR;
    int cb  = ((lin & ((1 << LOG2CPR) - 1)) * 16) ^ ((row & 7) << 4);
    gl_lds16(src + (size_t)row * srcStride + (cb >> 1),
             lds + (size_t)(i*256 + wid*64) * 8);          // wave-uniform LDS base
  }
}

// ---------------- fused f32 -> bf16 convert (x, wq, wk, wv, wo) ----------------
__global__ __launch_bounds__(256) void cvt5_kernel(
    const float* __restrict__ x,  const float* __restrict__ wq,
    const float* __restrict__ wk, const float* __restrict__ wv,
    const float* __restrict__ wo, u16* __restrict__ xb,
    u16* __restrict__ wqkv, u16* __restrict__ wob){
  int i = blockIdx.x * 256 + threadIdx.x;          // [0, 6291456)
  const float* src; u16* dst; int off;
  if      (i < 2097152){ src = x;  dst = xb;             off = i;           }
  else if (i < 3145728){ src = wq; dst = wqkv;           off = i - 2097152; }
  else if (i < 4194304){ src = wk; dst = wqkv + 4194304; off = i - 3145728; }
  else if (i < 5242880){ src = wv; dst = wqkv + 8388608; off = i - 4194304; }
  else                 { src = wo; dst = wob;            off = i - 5242880; }
  float4 v = ((const float4*)src)[off];
  uint2 o;
  o.x = (u32)f2b(v.x) | ((u32)f2b(v.y) << 16);
  o.y = (u32)f2b(v.z) | ((u32)f2b(v.w) << 16);
  ((uint2*)dst)[off] = o;
}

// ---------------- GEMM C = A * B^T  (A [M][K] bf16 rm, Bw [N][K] bf16 rm) ----------------
// 128x128 tile, BK=64, 4 waves (2x2, each 64x64), mfma 16x16x32 bf16.
// EPI 0: write f32 to C [M][N].  EPI 1: scatter bf16 into Q/K/V [B,NH,S,HD].
template<int EPI>
__global__ __launch_bounds__(256) void gemm_bt(
    const u16* __restrict__ A, const u16* __restrict__ Bw,
    float* __restrict__ C, u16* __restrict__ Qd, u16* __restrict__ Kd, u16* __restrict__ Vd,
    int M, int N, int K)
{
  __shared__ __align__(16) u16 As[128*64];
  __shared__ __align__(16) u16 Bs[128*64];
  const int tid  = threadIdx.x, lane = tid & 63, wid = tid >> 6;
  const int wr   = wid >> 1, wc = wid & 1;
  const int lrow = lane & 15, lk = lane >> 4;
  const int RB = blockIdx.y * 128, CB = blockIdx.x * 128;
  f32x4 acc[4][4] = {};

  for (int k0 = 0; k0 < K; k0 += 64){
    __syncthreads();
    stage_swz<3>(A  + (size_t)RB * K + k0, K, As, tid);
    stage_swz<3>(Bw + (size_t)CB * K + k0, K, Bs, tid);
    __syncthreads();
#pragma unroll
    for (int kk = 0; kk < 2; ++kk){
      short8 af[4], bf[4];
#pragma unroll
      for (int m = 0; m < 4; ++m){
        int row = wr*64 + m*16 + lrow;
        int cb  = (kk*64 + lk*16) ^ ((row & 7) << 4);
        af[m] = *(const short8*)&As[row*64 + (cb >> 1)];
      }
#pragma unroll
      for (int n = 0; n < 4; ++n){
        int row = wc*64 + n*16 + lrow;
        int cb  = (kk*64 + lk*16) ^ ((row & 7) << 4);
        bf[n] = *(const short8*)&Bs[row*64 + (cb >> 1)];
      }
#pragma unroll
      for (int m = 0; m < 4; ++m)
#pragma unroll
        for (int n = 0; n < 4; ++n)
          acc[m][n] = mfma_bf16(af[m], bf[n], acc[m][n]);
    }
  }

#pragma unroll
  for (int m = 0; m < 4; ++m){
#pragma unroll
    for (int n = 0; n < 4; ++n){
#pragma unroll
      for (int r = 0; r < 4; ++r){
        int row = RB + wr*64 + m*16 + lk*4 + r;
        int col = CB + wc*64 + n*16 + lrow;
        float v = acc[m][n][r];
        if constexpr (EPI == 0){
          C[(size_t)row * N + col] = v;
        } else {
          int which = col >> 11;
          int hd = col & 2047;
          int h = hd >> 7, d = hd & 127;
          int b = row >> 11, s = row & 2047;
          u16* dst = (which == 0) ? Qd : (which == 1) ? Kd : Vd;
          dst[(((size_t)(b*NH_ + h)) * S_ + s) * HD_ + d] = f2b(v);
        }
      }
    }
  }
}

// ---------------- RoPE, K only (Q rope is fused into attn's Q-frag load) ----------------
__global__ __launch_bounds__(256) void rope_k_kernel(u16* __restrict__ K,
                                                     const float* __restrict__ F){
  int idx = blockIdx.x * 256 + threadIdx.x;   // BH*S*64
  int d2 = idx & 63;
  int s  = (idx >> 6) & (S_ - 1);
  int bh = idx >> 17;
  size_t off = ((size_t)bh * S_ + s) * HD_ + d2*2;
  float c = F[s*128 + d2*2], sn = F[s*128 + d2*2 + 1];
  u32 kp = *(const u32*)(K + off);
  float tr = b2f((u16)kp), ti = b2f((u16)(kp >> 16));
  *(u32*)(K + off) = (u32)f2b(tr*c - ti*sn) | ((u32)f2b(tr*sn + ti*c) << 16);
}

// ---------------- V transpose: [BH,S,HD] -> [BH,HD,S] ----------------
__global__ void transpose_v(const u16* __restrict__ V, u16* __restrict__ Vt){
  __shared__ u16 t[32][33];
  int s0 = blockIdx.x * 32, d0 = blockIdx.y * 32, bh = blockIdx.z;
  const u16* vb = V  + (size_t)bh * S_ * HD_;
  u16*       tb = Vt + (size_t)bh * HD_ * S_;
  int tx = threadIdx.x, ty = threadIdx.y;
#pragma unroll
  for (int i = 0; i < 4; ++i)
    t[ty + i*8][tx] = vb[(size_t)(s0 + ty + i*8) * HD_ + d0 + tx];
  __syncthreads();
#pragma unroll
  for (int i = 0; i < 4; ++i)
    tb[(size_t)(d0 + ty + i*8) * S_ + s0 + tx] = t[tx][ty + i*8];
}

// ---------------- Flash attention (causal), pair-balanced, QBLK=64 (R8 structure) ----
// 512 blocks (2/CU, de-phased TLP). Each block: TWO complementary 64-row q-stripes,
// qb_hi = 31-x (long) then qb_lo = x (short, K/V prefix L2-warm); 33 tiles/block,
// uniform. 4 waves x 16 q rows. KVBLK=64, double-buffered K/V via global_load_lds
// (stage for tile t+1 issued at top of tile t -> one __syncthreads per tile).
// Q-RoPE fused into the Q-fragment load (pairs are intra-register; cos/sin from F).
// Swapped QK^T: S^T[kv][q] = mfma(A=K, B=Q)  -> per-lane softmax (q = lane&15).
// Flipped PV:   O^T[d][q]  = mfma(A=V^T, B=P) -> no cross-lane rescale/normalize.
// Scores in log2 domain (log2e folded into Q scale); softmax = exp2.
__global__ __launch_bounds__(256) void attn_kernel(
    const u16* __restrict__ Q, const u16* __restrict__ K, const u16* __restrict__ Vt,
    const float* __restrict__ F, u16* __restrict__ O)
{
  __shared__ __align__(16) u16 Ks[2][64*128];  // [kv][d], swizzled    32 KB
  __shared__ __align__(16) u16 Vs[2][128*64];  // [d][kv], swizzled    32 KB
  __shared__ __align__(16) u16 Ps[4][16*64];   // per-wave P [16q][64kv], XOR-swz  8 KB
  const int tid  = threadIdx.x, lane = tid & 63, wid = tid >> 6;
  const int lrow = lane & 15, lk = lane >> 4;

  // XCD-locality swizzle: lin%8 = XCD (heuristic); bh ≡ XCD (mod 8) ->
  // 4 distinct bh per XCD -> K/V working set ~4MB = one L2.
  const int lin = blockIdx.x;
  const int bh  = (lin & 7) | ((lin >> 7) << 3);
  const int x   = (lin >> 3) & 15;

  const u16* Kb  = K  + (size_t)bh * S_ * HD_;
  const u16* Vtb = Vt + (size_t)bh * HD_ * S_;
  const int b = bh >> 4, h = bh & 15;
  u16* const pw = &Ps[wid][0];

  for (int pass = 0; pass < 2; ++pass){
    const int qb = pass ? x : (31 - x);
    const int q0 = qb * 64;
    const int ntile = qb + 1;
    const int qg = q0 + wid*16 + lrow;        // this lane's q row (B-frag col)

    // Q fragments (B-operand) with fused RoPE+scale: col q = qg, k = kc*32+lk*8+j
    short8 qf[4];
    {
      const u16* qp_ = Q + ((size_t)bh * S_ + qg) * HD_;
      const float* Fq = F + (size_t)qg * 128;
#pragma unroll
      for (int kc = 0; kc < 4; ++kc){
        short8 q = *(const short8*)&qp_[kc*32 + lk*8];
        float4 fa = *(const float4*)&Fq[kc*32 + lk*8];
        float4 fb = *(const float4*)&Fq[kc*32 + lk*8 + 4];
        uint4 w;
        w.x = rot2((u16)q[0], (u16)q[1], fa.x, fa.y, QSCALE);
        w.y = rot2((u16)q[2], (u16)q[3], fa.z, fa.w, QSCALE);
        w.z = rot2((u16)q[4], (u16)q[5], fb.x, fb.y, QSCALE);
        w.w = rot2((u16)q[6], (u16)q[7], fb.z, fb.w, QSCALE);
        qf[kc] = __builtin_bit_cast(short8, w);
      }
    }

    f32x4 acco[8] = {};
    float m_ = -3.0e38f, l_ = 0.0f;

    int cur = 0;
    stage_swz<4>(Kb,  HD_, &Ks[0][0], tid);
    stage_swz<3>(Vtb, S_,  &Vs[0][0], tid);
    __syncthreads();

    for (int t = 0; t < ntile; ++t){
      if (t + 1 < ntile){                      // issue next-tile stage; flies under compute
        stage_swz<4>(Kb  + (size_t)(t+1)*64*HD_, HD_, &Ks[cur^1][0], tid);
        stage_swz<3>(Vtb + (t+1)*64,             S_,  &Vs[cur^1][0], tid);
      }
      const int kv0 = t*64;
      const u16* ks = &Ks[cur][0];
      const u16* vs = &Vs[cur][0];

      // ---- QK^T (swapped): sc[nt] = S^T[kv][q] ----
      f32x4 sc[4] = {};
      __builtin_amdgcn_s_setprio(1);
#pragma unroll
      for (int nt = 0; nt < 4; ++nt){
        int row = nt*16 + lrow;
#pragma unroll
        for (int kc = 0; kc < 4; ++kc){
          int cb = (kc*64 + lk*16) ^ ((row & 7) << 4);
          short8 kf = *(const short8*)&ks[row*128 + (cb >> 1)];
          sc[nt] = mfma_bf16(kf, qf[kc], sc[nt]);
        }
      }
      __builtin_amdgcn_s_setprio(0);

      if (t == ntile - 1){   // diagonal tile: causal mask
#pragma unroll
        for (int nt = 0; nt < 4; ++nt)
#pragma unroll
          for (int r = 0; r < 4; ++r)
            if (kv0 + nt*16 + lk*4 + r > qg) sc[nt][r] = -1.0e30f;
      }

      // ---- per-lane online softmax (exp2 domain) + P pack/store ----
      {
        float pmax = sc[0][0];
#pragma unroll
        for (int nt = 0; nt < 4; ++nt)
#pragma unroll
          for (int r = 0; r < 4; ++r) pmax = fmaxf(pmax, sc[nt][r]);
        pmax = fmaxf(pmax, __shfl_xor(pmax, 16));
        pmax = fmaxf(pmax, __shfl_xor(pmax, 32));
        if (!__all(pmax - m_ <= 11.0f)){        // defer-max (log2-domain THR)
          float mn = fmaxf(m_, pmax);
          float c = exp2f(m_ - mn);
          l_ *= c;
#pragma unroll
          for (int dt = 0; dt < 8; ++dt)
#pragma unroll
            for (int r = 0; r < 4; ++r) acco[dt][r] *= c;
          m_ = mn;
        }
        float rs = 0.0f;
#pragma unroll
        for (int nt = 0; nt < 4; ++nt)
#pragma unroll
          for (int r = 0; r < 4; ++r){
            float p = exp2f(sc[nt][r] - m_);
            sc[nt][r] = p;
            rs += p;
          }
        rs += __shfl_xor(rs, 16);
        rs += __shfl_xor(rs, 32);
        l_ += rs;
#pragma unroll
        for (int nt = 0; nt < 4; ++nt){
          uint2 wv;
          wv.x = cvt_pk_bf16(sc[nt][0], sc[nt][1]);
          wv.y = cvt_pk_bf16(sc[nt][2], sc[nt][3]);
          int boff = (nt*32 + lk*8) ^ ((lrow & 7) << 4);
          *(uint2*)((char*)&pw[lrow*64] + boff) = wv;
        }
      }

      // ---- PV (flipped): acco[dt] += V^T x P ----
#pragma unroll
      for (int kc2 = 0; kc2 < 2; ++kc2){
        int pboff = (kc2*64 + lk*16) ^ ((lrow & 7) << 4);
        short8 pf = *(const short8*)((const char*)&pw[lrow*64] + pboff);
        __builtin_amdgcn_s_setprio(1);
#pragma unroll
        for (int dt = 0; dt < 8; ++dt){
          int row = dt*16 + lrow;
          int cb = (kc2*64 + lk*16) ^ ((row & 7) << 4);
          short8 vf = *(const short8*)&vs[row*64 + (cb >> 1)];
          acco[dt] = mfma_bf16(vf, pf, acco[dt]);
        }
        __builtin_amdgcn_s_setprio(0);
      }

      __syncthreads();     // drains vmcnt(0): staged loads had the whole tile to land
      cur ^= 1;
    }

    // ---- epilogue: normalize + packed store ----
    {
      float inv = 1.0f / l_;
      u16* ob = O + ((size_t)(b*S_ + qg)) * H_ + h*128;
#pragma unroll
      for (int dt = 0; dt < 8; ++dt){
        uint2 wv;
        wv.x = cvt_pk_bf16(acco[dt][0]*inv, acco[dt][1]*inv);
        wv.y = cvt_pk_bf16(acco[dt][2]*inv, acco[dt][3]*inv);
        *(uint2*)&ob[dt*16 + lk*4] = wv;
      }
    }
    __syncthreads();       // pass boundary: LDS reuse safe
  }
}

// ---------------- launch ----------------
extern "C" void kernel_launch(void* const* d_in, const int* in_sizes, int n_in,
                              void* d_out, int out_size, void* d_ws, size_t ws_size,
                              hipStream_t stream)
{
  (void)in_sizes; (void)n_in; (void)out_size; (void)ws_size;
  const float* x  = (const float*)d_in[0];
  const float* fc = (const float*)d_in[1];   // freqs_cis [S,64,2]
  const float* wq = (const float*)d_in[3];
  const float* wk = (const float*)d_in[4];
  const float* wv = (const float*)d_in[5];
  const float* wo = (const float*)d_in[6];

  char* w = (char*)d_ws;
  u16* xb   = (u16*)(w);                 // [4096,2048] bf16
  u16* wqkv = (u16*)(w + 16777216);      // [6144,2048] bf16
  u16* wob  = (u16*)(w + 41943040);      // [2048,2048] bf16
  u16* Qr   = (u16*)(w + 50331648);      // [BH,S,HD]   bf16 (unroped; rope fused in attn)
  u16* Kr   = (u16*)(w + 67108864);      // [BH,S,HD]   bf16
  u16* Vr   = (u16*)(w + 83886080);      // [BH,S,HD]   bf16
  u16* Vt   = (u16*)(w + 100663296);     // [BH,HD,S]   bf16
  u16* aO   = (u16*)(w + 117440512);     // [B,S,H]     bf16 (attn out)
  float* out = (float*)d_out;

  cvt5_kernel<<<24576, 256, 0, stream>>>(x, wq, wk, wv, wo, xb, wqkv, wob);

  gemm_bt<1><<<dim3(48, 32), 256, 0, stream>>>(xb, wqkv, nullptr, Qr, Kr, Vr, 4096, 6144, 2048);
  rope_k_kernel<<<16384, 256, 0, stream>>>(Kr, fc);
  transpose_v<<<dim3(64, 4, 32), dim3(32, 8), 0, stream>>>(Vr, Vt);
  attn_kernel<<<512, 256, 0, stream>>>(Qr, Kr, Vt, fc, aO);
  gemm_bt<0><<<dim3(16, 32), 256, 0, stream>>>(aO, wob, out, nullptr, nullptr, nullptr, 4096, 2048, 2048);
}

// Round 12
// 275.172 us; speedup vs baseline: 1.1496x; 1.0037x over previous
//
#include <hip/hip_runtime.h>

#define DEVI __device__ __forceinline__

typedef unsigned short u16;
typedef unsigned int   u32;
typedef __attribute__((ext_vector_type(4))) float f32x4;
typedef __attribute__((ext_vector_type(8))) short short8;
typedef __attribute__((ext_vector_type(8))) __bf16 bf16x8;

#define B_   2
#define S_   2048
#define H_   2048
#define NH_  16
#define HD_  128
#define BH_  (B_*NH_)
// 1/sqrt(128) * log2(e)  -> scores land in log2 domain, softmax uses exp2
#define QSCALE 0.12751743f

DEVI u16 f2b(float f){                       // f32 -> bf16 bits, RNE
  u32 u = __builtin_bit_cast(u32, f);
  u32 r = (u + 0x7fffu + ((u >> 16) & 1u)) >> 16;
  return (u16)r;
}
DEVI float b2f(u16 h){
  u32 u = ((u32)h) << 16;
  return __builtin_bit_cast(float, u);
}
DEVI u32 cvt_pk_bf16(float lo, float hi){    // word = {lo: bf16(lo), hi: bf16(hi)}
  u32 r; asm("v_cvt_pk_bf16_f32 %0, %1, %2" : "=v"(r) : "v"(lo), "v"(hi)); return r;
}
DEVI u32 rot2(u16 lo, u16 hi, float c, float s, float scale){  // RoPE one (even,odd) pair
  float tr = b2f(lo), ti = b2f(hi);
  return cvt_pk_bf16((tr*c - ti*s)*scale, (tr*s + ti*c)*scale);
}
DEVI f32x4 mfma_bf16(short8 a, short8 b, f32x4 c){
  return __builtin_amdgcn_mfma_f32_16x16x32_bf16(
      __builtin_bit_cast(bf16x8, a), __builtin_bit_cast(bf16x8, b), c, 0, 0, 0);
}
DEVI void gl_lds16(const void* g, void* l){
  __builtin_amdgcn_global_load_lds((const __attribute__((address_space(1))) void*)g,
                                   (__attribute__((address_space(3))) void*)l, 16, 0, 0);
}

// Stage a 16KB tile (1024 x 16B chunks) into LDS with XOR swizzle applied on the
// GLOBAL source column (LDS dest stays linear; read side applies the same XOR).
// 256-thread version (old GEMM + attn).
template<int LOG2CPR>
DEVI void stage_swz(const u16* __restrict__ src, int srcStride /*elems*/, u16* lds, int tid){
  const int wid = tid >> 6, lane = tid & 63;
#pragma unroll
  for (int i = 0; i < 4; ++i){
    int lin = i*256 + wid*64 + lane;                       // 16B chunk index
    int row = lin >> LOG2CPR;
    int cb  = ((lin & ((1 << LOG2CPR) - 1)) * 16) ^ ((row & 7) << 4);
    gl_lds16(src + (size_t)row * srcStride + (cb >> 1),
             lds + (size_t)(i*256 + wid*64) * 8);          // wave-uniform LDS base
  }
}

// 512-thread staging: two 512-chunk groups (16B/thread each) of a row-major
// [rows][64]-bf16 region with stride 2048; source pre-swizzled, LDS linear.
DEVI void stage2(const u16* __restrict__ src, u16* lds, int tid, int it0){
#pragma unroll
  for (int i = it0; i < it0 + 2; ++i){
    int lin = i*512 + tid;
    int row = lin >> 3;                                    // 8 chunks per 64-elem row
    int cb  = ((lin & 7) * 16) ^ ((row & 7) << 4);
    gl_lds16(src + (size_t)row * 2048 + (cb >> 1),
             lds + (size_t)(i*512 + (tid & ~63)) * 8);     // wave-uniform LDS base
  }
}

// ---------------- fused f32 -> bf16 convert (x, wq, wk, wv, wo) ----------------
__global__ __launch_bounds__(256) void cvt5_kernel(
    const float* __restrict__ x,  const float* __restrict__ wq,
    const float* __restrict__ wk, const float* __restrict__ wv,
    const float* __restrict__ wo, u16* __restrict__ xb,
    u16* __restrict__ wqkv, u16* __restrict__ wob){
  int i = blockIdx.x * 256 + threadIdx.x;          // [0, 6291456)
  const float* src; u16* dst; int off;
  if      (i < 2097152){ src = x;  dst = xb;             off = i;           }
  else if (i < 3145728){ src = wq; dst = wqkv;           off = i - 2097152; }
  else if (i < 4194304){ src = wk; dst = wqkv + 4194304; off = i - 3145728; }
  else if (i < 5242880){ src = wv; dst = wqkv + 8388608; off = i - 4194304; }
  else                 { src = wo; dst = wob;            off = i - 5242880; }
  float4 v = ((const float4*)src)[off];
  uint2 o;
  o.x = (u32)f2b(v.x) | ((u32)f2b(v.y) << 16);
  o.y = (u32)f2b(v.z) | ((u32)f2b(v.w) << 16);
  ((uint2*)dst)[off] = o;
}

// ---------------- 8-phase QKV GEMM: C = A * B^T, scatter into Q/K/V -----------
// BM=256, BN=128, BK=64, 512 threads (8 waves 2Mx4N, per-wave 128x32 out).
// Triple-buffered K-tile slots (48 KB each: A 32K + B 16K) -> counted vmcnt(6)
// at tile boundaries (waits tile t+1's 6 loads, leaves t+2's 6 in flight).
// Per tile: 4 phases x {6 ds_read_b128 | 2 stage-issues | barrier | 8 MFMA | barrier}.
// grid = 16 M-tiles x 48 N-tiles = 768 blocks = 3 full rounds at 1 block/CU.
#define G8_NT 32   // K/BK = 2048/64
__global__ __launch_bounds__(512) void gemm8_qkv(
    const u16* __restrict__ A, const u16* __restrict__ Bw,
    u16* __restrict__ Qd, u16* __restrict__ Kd, u16* __restrict__ Vd)
{
  extern __shared__ __align__(16) u16 lds[];   // 3 * 24576 u16 = 147456 B
  const int tid = threadIdx.x, lane = tid & 63, wid = tid >> 6;
  const int wm = wid >> 2, wn = wid & 3;
  const int lrow = lane & 15, lk = lane >> 4;
  // XCD swizzle (768 % 8 == 0 -> simple form is bijective)
  const int swzb = (blockIdx.x & 7) * 96 + (blockIdx.x >> 3);
  const int RB = (swzb / 48) * 256, CB = (swzb % 48) * 128;
  const u16* Ab = A  + (size_t)RB * 2048;
  const u16* Bb = Bw + (size_t)CB * 2048;

  f32x4 acc[8][2] = {};

#define AS_(s) (lds + (s) * 24576)
#define BS_(s) (lds + (s) * 24576 + 16384)

  // prologue: stage tiles 0 -> slot0, 1 -> slot1 (6 loads each)
  stage2(Ab,      AS_(0), tid, 0);  stage2(Ab,      AS_(0), tid, 2);
  stage2(Bb,      BS_(0), tid, 0);
  stage2(Ab + 64, AS_(1), tid, 0);  stage2(Ab + 64, AS_(1), tid, 2);
  stage2(Bb + 64, BS_(1), tid, 0);
  asm volatile("s_waitcnt vmcnt(6)" ::: "memory");   // tile 0 landed
  __builtin_amdgcn_s_barrier();

  for (int t = 0; t < G8_NT; ++t){
    const u16* as = AS_(t % 3);
    const u16* bs = BS_(t % 3);
    const int  ns = (t + 2) % 3;
    const bool st = (t + 2 < G8_NT);
    const u16* an = Ab + (t + 2) * 64;
    const u16* bn = Bb + (t + 2) * 64;

#pragma unroll
    for (int ph = 0; ph < 4; ++ph){
      const int mh = ph & 1, kh = ph >> 1;
      short8 af[4], bf[2];
#pragma unroll
      for (int i = 0; i < 4; ++i){
        int row = wm*128 + (mh*4 + i)*16 + lrow;
        int cb  = (kh*64 + lk*16) ^ ((row & 7) << 4);
        af[i] = *(const short8*)&as[row*64 + (cb >> 1)];
      }
#pragma unroll
      for (int j = 0; j < 2; ++j){
        int row = wn*32 + j*16 + lrow;
        int cb  = (kh*64 + lk*16) ^ ((row & 7) << 4);
        bf[j] = *(const short8*)&bs[row*64 + (cb >> 1)];
      }
      if (st){
        if      (ph == 0) stage2(an, AS_(ns), tid, 0);
        else if (ph == 1) stage2(an, AS_(ns), tid, 2);
        else if (ph == 2) stage2(bn, BS_(ns), tid, 0);
      }
      __builtin_amdgcn_s_barrier();
      __builtin_amdgcn_s_setprio(1);
#pragma unroll
      for (int i = 0; i < 4; ++i)
#pragma unroll
        for (int j = 0; j < 2; ++j)
          acc[mh*4 + i][j] = mfma_bf16(af[i], bf[j], acc[mh*4 + i][j]);
      __builtin_amdgcn_s_setprio(0);
      if (ph < 3) __builtin_amdgcn_s_barrier();
    }
    // tile boundary: each wave waits ITS loads for tile t+1, then block barrier.
    if (st)                   asm volatile("s_waitcnt vmcnt(6)" ::: "memory");
    else if (t + 1 < G8_NT)   asm volatile("s_waitcnt vmcnt(0)" ::: "memory");
    __builtin_amdgcn_s_barrier();
  }

  // epilogue: scatter bf16 into Q/K/V [B,NH,S,HD]
#pragma unroll
  for (int fm = 0; fm < 8; ++fm){
#pragma unroll
    for (int fn = 0; fn < 2; ++fn){
      const int col  = CB + wn*32 + fn*16 + lrow;
      const int row0 = RB + wm*128 + fm*16 + lk*4;
      const int which = col >> 11;
      const int hd = col & 2047;
      const int h = hd >> 7, d = hd & 127;
      const int b = row0 >> 11, s0 = row0 & 2047;
      u16* dst = (which == 0) ? Qd : (which == 1) ? Kd : Vd;
      size_t base = (((size_t)(b*NH_ + h)) * S_ + s0) * HD_ + d;
#pragma unroll
      for (int r = 0; r < 4; ++r)
        dst[base + (size_t)r * HD_] = f2b(acc[fm][fn][r]);
    }
  }
#undef AS_
#undef BS_
}

// ---------------- GEMM C = A * B^T (old 128^2 2-phase; used for out-proj) ------
template<int EPI>
__global__ __launch_bounds__(256) void gemm_bt(
    const u16* __restrict__ A, const u16* __restrict__ Bw,
    float* __restrict__ C, u16* __restrict__ Qd, u16* __restrict__ Kd, u16* __restrict__ Vd,
    int M, int N, int K)
{
  __shared__ __align__(16) u16 As[128*64];
  __shared__ __align__(16) u16 Bs[128*64];
  const int tid  = threadIdx.x, lane = tid & 63, wid = tid >> 6;
  const int wr   = wid >> 1, wc = wid & 1;
  const int lrow = lane & 15, lk = lane >> 4;
  const int RB = blockIdx.y * 128, CB = blockIdx.x * 128;
  f32x4 acc[4][4] = {};

  for (int k0 = 0; k0 < K; k0 += 64){
    __syncthreads();
    stage_swz<3>(A  + (size_t)RB * K + k0, K, As, tid);
    stage_swz<3>(Bw + (size_t)CB * K + k0, K, Bs, tid);
    __syncthreads();
#pragma unroll
    for (int kk = 0; kk < 2; ++kk){
      short8 af[4], bf[4];
#pragma unroll
      for (int m = 0; m < 4; ++m){
        int row = wr*64 + m*16 + lrow;
        int cb  = (kk*64 + lk*16) ^ ((row & 7) << 4);
        af[m] = *(const short8*)&As[row*64 + (cb >> 1)];
      }
#pragma unroll
      for (int n = 0; n < 4; ++n){
        int row = wc*64 + n*16 + lrow;
        int cb  = (kk*64 + lk*16) ^ ((row & 7) << 4);
        bf[n] = *(const short8*)&Bs[row*64 + (cb >> 1)];
      }
#pragma unroll
      for (int m = 0; m < 4; ++m)
#pragma unroll
        for (int n = 0; n < 4; ++n)
          acc[m][n] = mfma_bf16(af[m], bf[n], acc[m][n]);
    }
  }

#pragma unroll
  for (int m = 0; m < 4; ++m){
#pragma unroll
    for (int n = 0; n < 4; ++n){
#pragma unroll
      for (int r = 0; r < 4; ++r){
        int row = RB + wr*64 + m*16 + lk*4 + r;
        int col = CB + wc*64 + n*16 + lrow;
        float v = acc[m][n][r];
        if constexpr (EPI == 0){
          C[(size_t)row * N + col] = v;
        } else {
          int which = col >> 11;
          int hd = col & 2047;
          int h = hd >> 7, d = hd & 127;
          int b = row >> 11, s = row & 2047;
          u16* dst = (which == 0) ? Qd : (which == 1) ? Kd : Vd;
          dst[(((size_t)(b*NH_ + h)) * S_ + s) * HD_ + d] = f2b(v);
        }
      }
    }
  }
}

// ---------------- RoPE, K only (Q rope is fused into attn's Q-frag load) ----------------
__global__ __launch_bounds__(256) void rope_k_kernel(u16* __restrict__ K,
                                                     const float* __restrict__ F){
  int idx = blockIdx.x * 256 + threadIdx.x;   // BH*S*64
  int d2 = idx & 63;
  int s  = (idx >> 6) & (S_ - 1);
  int bh = idx >> 17;
  size_t off = ((size_t)bh * S_ + s) * HD_ + d2*2;
  float c = F[s*128 + d2*2], sn = F[s*128 + d2*2 + 1];
  u32 kp = *(const u32*)(K + off);
  float tr = b2f((u16)kp), ti = b2f((u16)(kp >> 16));
  *(u32*)(K + off) = (u32)f2b(tr*c - ti*sn) | ((u32)f2b(tr*sn + ti*c) << 16);
}

// ---------------- V transpose: [BH,S,HD] -> [BH,HD,S] ----------------
__global__ void transpose_v(const u16* __restrict__ V, u16* __restrict__ Vt){
  __shared__ u16 t[32][33];
  int s0 = blockIdx.x * 32, d0 = blockIdx.y * 32, bh = blockIdx.z;
  const u16* vb = V  + (size_t)bh * S_ * HD_;
  u16*       tb = Vt + (size_t)bh * HD_ * S_;
  int tx = threadIdx.x, ty = threadIdx.y;
#pragma unroll
  for (int i = 0; i < 4; ++i)
    t[ty + i*8][tx] = vb[(size_t)(s0 + ty + i*8) * HD_ + d0 + tx];
  __syncthreads();
#pragma unroll
  for (int i = 0; i < 4; ++i)
    tb[(size_t)(d0 + ty + i*8) * S_ + s0 + tx] = t[tx][ty + i*8];
}

// ---------------- Flash attention (causal), pair-balanced, QBLK=64 (R8 structure) ----
__global__ __launch_bounds__(256) void attn_kernel(
    const u16* __restrict__ Q, const u16* __restrict__ K, const u16* __restrict__ Vt,
    const float* __restrict__ F, u16* __restrict__ O)
{
  __shared__ __align__(16) u16 Ks[2][64*128];  // [kv][d], swizzled    32 KB
  __shared__ __align__(16) u16 Vs[2][128*64];  // [d][kv], swizzled    32 KB
  __shared__ __align__(16) u16 Ps[4][16*64];   // per-wave P [16q][64kv], XOR-swz  8 KB
  const int tid  = threadIdx.x, lane = tid & 63, wid = tid >> 6;
  const int lrow = lane & 15, lk = lane >> 4;

  const int lin = blockIdx.x;
  const int bh  = (lin & 7) | ((lin >> 7) << 3);   // bh ≡ XCD (mod 8) -> L2 locality
  const int x   = (lin >> 3) & 15;

  const u16* Kb  = K  + (size_t)bh * S_ * HD_;
  const u16* Vtb = Vt + (size_t)bh * HD_ * S_;
  const int b = bh >> 4, h = bh & 15;
  u16* const pw = &Ps[wid][0];

  for (int pass = 0; pass < 2; ++pass){
    const int qb = pass ? x : (31 - x);
    const int q0 = qb * 64;
    const int ntile = qb + 1;
    const int qg = q0 + wid*16 + lrow;        // this lane's q row (B-frag col)

    // Q fragments (B-operand) with fused RoPE+scale: col q = qg, k = kc*32+lk*8+j
    short8 qf[4];
    {
      const u16* qp_ = Q + ((size_t)bh * S_ + qg) * HD_;
      const float* Fq = F + (size_t)qg * 128;
#pragma unroll
      for (int kc = 0; kc < 4; ++kc){
        short8 q = *(const short8*)&qp_[kc*32 + lk*8];
        float4 fa = *(const float4*)&Fq[kc*32 + lk*8];
        float4 fb = *(const float4*)&Fq[kc*32 + lk*8 + 4];
        uint4 w;
        w.x = rot2((u16)q[0], (u16)q[1], fa.x, fa.y, QSCALE);
        w.y = rot2((u16)q[2], (u16)q[3], fa.z, fa.w, QSCALE);
        w.z = rot2((u16)q[4], (u16)q[5], fb.x, fb.y, QSCALE);
        w.w = rot2((u16)q[6], (u16)q[7], fb.z, fb.w, QSCALE);
        qf[kc] = __builtin_bit_cast(short8, w);
      }
    }

    f32x4 acco[8] = {};
    float m_ = -3.0e38f, l_ = 0.0f;

    int cur = 0;
    stage_swz<4>(Kb,  HD_, &Ks[0][0], tid);
    stage_swz<3>(Vtb, S_,  &Vs[0][0], tid);
    __syncthreads();

    for (int t = 0; t < ntile; ++t){
      if (t + 1 < ntile){                      // issue next-tile stage; flies under compute
        stage_swz<4>(Kb  + (size_t)(t+1)*64*HD_, HD_, &Ks[cur^1][0], tid);
        stage_swz<3>(Vtb + (t+1)*64,             S_,  &Vs[cur^1][0], tid);
      }
      const int kv0 = t*64;
      const u16* ks = &Ks[cur][0];
      const u16* vs = &Vs[cur][0];

      // ---- QK^T (swapped): sc[nt] = S^T[kv][q] ----
      f32x4 sc[4] = {};
      __builtin_amdgcn_s_setprio(1);
#pragma unroll
      for (int nt = 0; nt < 4; ++nt){
        int row = nt*16 + lrow;
#pragma unroll
        for (int kc = 0; kc < 4; ++kc){
          int cb = (kc*64 + lk*16) ^ ((row & 7) << 4);
          short8 kf = *(const short8*)&ks[row*128 + (cb >> 1)];
          sc[nt] = mfma_bf16(kf, qf[kc], sc[nt]);
        }
      }
      __builtin_amdgcn_s_setprio(0);

      if (t == ntile - 1){   // diagonal tile: causal mask
#pragma unroll
        for (int nt = 0; nt < 4; ++nt)
#pragma unroll
          for (int r = 0; r < 4; ++r)
            if (kv0 + nt*16 + lk*4 + r > qg) sc[nt][r] = -1.0e30f;
      }

      // ---- per-lane online softmax (exp2 domain) + P pack/store ----
      {
        float pmax = sc[0][0];
#pragma unroll
        for (int nt = 0; nt < 4; ++nt)
#pragma unroll
          for (int r = 0; r < 4; ++r) pmax = fmaxf(pmax, sc[nt][r]);
        pmax = fmaxf(pmax, __shfl_xor(pmax, 16));
        pmax = fmaxf(pmax, __shfl_xor(pmax, 32));
        if (!__all(pmax - m_ <= 11.0f)){        // defer-max (log2-domain THR)
          float mn = fmaxf(m_, pmax);
          float c = exp2f(m_ - mn);
          l_ *= c;
#pragma unroll
          for (int dt = 0; dt < 8; ++dt)
#pragma unroll
            for (int r = 0; r < 4; ++r) acco[dt][r] *= c;
          m_ = mn;
        }
        float rs = 0.0f;
#pragma unroll
        for (int nt = 0; nt < 4; ++nt)
#pragma unroll
          for (int r = 0; r < 4; ++r){
            float p = exp2f(sc[nt][r] - m_);
            sc[nt][r] = p;
            rs += p;
          }
        rs += __shfl_xor(rs, 16);
        rs += __shfl_xor(rs, 32);
        l_ += rs;
#pragma unroll
        for (int nt = 0; nt < 4; ++nt){
          uint2 wv;
          wv.x = cvt_pk_bf16(sc[nt][0], sc[nt][1]);
          wv.y = cvt_pk_bf16(sc[nt][2], sc[nt][3]);
          int boff = (nt*32 + lk*8) ^ ((lrow & 7) << 4);
          *(uint2*)((char*)&pw[lrow*64] + boff) = wv;
        }
      }

      // ---- PV (flipped): acco[dt] += V^T x P ----
#pragma unroll
      for (int kc2 = 0; kc2 < 2; ++kc2){
        int pboff = (kc2*64 + lk*16) ^ ((lrow & 7) << 4);
        short8 pf = *(const short8*)((const char*)&pw[lrow*64] + pboff);
        __builtin_amdgcn_s_setprio(1);
#pragma unroll
        for (int dt = 0; dt < 8; ++dt){
          int row = dt*16 + lrow;
          int cb = (kc2*64 + lk*16) ^ ((row & 7) << 4);
          short8 vf = *(const short8*)&vs[row*64 + (cb >> 1)];
          acco[dt] = mfma_bf16(vf, pf, acco[dt]);
        }
        __builtin_amdgcn_s_setprio(0);
      }

      __syncthreads();     // drains vmcnt(0): staged loads had the whole tile to land
      cur ^= 1;
    }

    // ---- epilogue: normalize + packed store ----
    {
      float inv = 1.0f / l_;
      u16* ob = O + ((size_t)(b*S_ + qg)) * H_ + h*128;
#pragma unroll
      for (int dt = 0; dt < 8; ++dt){
        uint2 wv;
        wv.x = cvt_pk_bf16(acco[dt][0]*inv, acco[dt][1]*inv);
        wv.y = cvt_pk_bf16(acco[dt][2]*inv, acco[dt][3]*inv);
        *(uint2*)&ob[dt*16 + lk*4] = wv;
      }
    }
    __syncthreads();       // pass boundary: LDS reuse safe
  }
}

// ---------------- launch ----------------
extern "C" void kernel_launch(void* const* d_in, const int* in_sizes, int n_in,
                              void* d_out, int out_size, void* d_ws, size_t ws_size,
                              hipStream_t stream)
{
  (void)in_sizes; (void)n_in; (void)out_size; (void)ws_size;
  const float* x  = (const float*)d_in[0];
  const float* fc = (const float*)d_in[1];   // freqs_cis [S,64,2]
  const float* wq = (const float*)d_in[3];
  const float* wk = (const float*)d_in[4];
  const float* wv = (const float*)d_in[5];
  const float* wo = (const float*)d_in[6];

  char* w = (char*)d_ws;
  u16* xb   = (u16*)(w);                 // [4096,2048] bf16
  u16* wqkv = (u16*)(w + 16777216);      // [6144,2048] bf16
  u16* wob  = (u16*)(w + 41943040);      // [2048,2048] bf16
  u16* Qr   = (u16*)(w + 50331648);      // [BH,S,HD]   bf16 (unroped; rope fused in attn)
  u16* Kr   = (u16*)(w + 67108864);      // [BH,S,HD]   bf16
  u16* Vr   = (u16*)(w + 83886080);      // [BH,S,HD]   bf16
  u16* Vt   = (u16*)(w + 100663296);     // [BH,HD,S]   bf16
  u16* aO   = (u16*)(w + 117440512);     // [B,S,H]     bf16 (attn out)
  float* out = (float*)d_out;

  (void)hipFuncSetAttribute((const void*)gemm8_qkv,
                            hipFuncAttributeMaxDynamicSharedMemorySize, 147456);

  cvt5_kernel<<<24576, 256, 0, stream>>>(x, wq, wk, wv, wo, xb, wqkv, wob);

  gemm8_qkv<<<768, 512, 147456, stream>>>(xb, wqkv, Qr, Kr, Vr);
  rope_k_kernel<<<16384, 256, 0, stream>>>(Kr, fc);
  transpose_v<<<dim3(64, 4, 32), dim3(32, 8), 0, stream>>>(Vr, Vt);
  attn_kernel<<<512, 256, 0, stream>>>(Qr, Kr, Vt, fc, aO);
  gemm_bt<0><<<dim3(16, 32), 256, 0, stream>>>(aO, wob, out, nullptr, nullptr, nullptr, 4096, 2048, 2048);
}